// Round 3
// baseline (12653.593 us; speedup 1.0000x reference)
//
#include <hip/hip_runtime.h>

typedef unsigned int uint;
typedef unsigned long long u64;
typedef _Float16 f16x2 __attribute__((ext_vector_type(2)));

#define SEQ 4096
#define EMB 300
#define HID 500
#define NG 2000      // 4*HID
#define KX 600       // 2*EMB
#define KXP 608      // padded K for aligned float4 loads

#define BM 64
#define BN 64
#define BK 16

#define NWG 50       // workgroups in recurrence
#define UPW 10       // hidden units per workgroup
#define RWS 40       // 4*UPW gate rows per workgroup
#define TPB 320      // 10 units * 32 lanes
#define HSLOT 512    // padded u32 h slots per double-buffer half

// ---------------------------------------------------------------- gather x
__global__ __launch_bounds__(256) void gather_x(const int* __restrict__ words,
                                                const int* __restrict__ labels,
                                                const float* __restrict__ embw,
                                                const float* __restrict__ embe,
                                                float* __restrict__ x) {
  int t = blockIdx.x;
  int w = words[t], l = labels[t];
  const float* rw = embw + (size_t)w * EMB;
  const float* re = embe + (size_t)l * EMB;
  float* xr = x + (size_t)t * KXP;
  for (int k = threadIdx.x; k < KXP; k += 256) {
    float v = 0.f;
    if (k < EMB) v = rw[k];
    else if (k < KX) v = re[k - EMB];
    xr[k] = v;  // pads [600,608) zeroed
  }
}

// ---------------------------------------------------------------- pre GEMM
// pre[t][n] = sum_k x[t][k] * Wih[n][k] + bih[n] + bhh[n]
__global__ __launch_bounds__(256) void gemm_pre(const float* __restrict__ x,
                                                const float* __restrict__ Wih,
                                                const float* __restrict__ bih,
                                                const float* __restrict__ bhh,
                                                float* __restrict__ pre) {
  __shared__ float As[BK][BM + 4];
  __shared__ float Bs[BK][BN + 4];
  const int m0 = blockIdx.x * BM;
  const int n0 = blockIdx.y * BN;
  const int tid = threadIdx.x;
  const int tx = tid & 15, ty = tid >> 4;
  const int lrow = tid >> 2;          // 0..63
  const int lc4 = (tid & 3) << 2;     // 0,4,8,12
  float acc[4][4] = {};

  for (int kk = 0; kk < KX; kk += BK) {
    float4 av = *(const float4*)(x + (size_t)(m0 + lrow) * KXP + kk + lc4);
    int brow = n0 + lrow; if (brow >= NG) brow = 0;
    float4 bv;
    if (kk + lc4 + 3 < KX) {
      bv = *(const float4*)(Wih + (size_t)brow * KX + kk + lc4);
    } else {
      float tmp[4];
#pragma unroll
      for (int j = 0; j < 4; ++j) {
        int k = kk + lc4 + j;
        tmp[j] = (k < KX) ? Wih[(size_t)brow * KX + k] : 0.f;
      }
      bv = make_float4(tmp[0], tmp[1], tmp[2], tmp[3]);
    }
    As[lc4 + 0][lrow] = av.x; As[lc4 + 1][lrow] = av.y;
    As[lc4 + 2][lrow] = av.z; As[lc4 + 3][lrow] = av.w;
    Bs[lc4 + 0][lrow] = bv.x; Bs[lc4 + 1][lrow] = bv.y;
    Bs[lc4 + 2][lrow] = bv.z; Bs[lc4 + 3][lrow] = bv.w;
    __syncthreads();
#pragma unroll
    for (int k = 0; k < BK; ++k) {
      float4 a = *(const float4*)&As[k][ty << 2];
      float4 b = *(const float4*)&Bs[k][tx << 2];
      acc[0][0] += a.x * b.x; acc[0][1] += a.x * b.y; acc[0][2] += a.x * b.z; acc[0][3] += a.x * b.w;
      acc[1][0] += a.y * b.x; acc[1][1] += a.y * b.y; acc[1][2] += a.y * b.z; acc[1][3] += a.y * b.w;
      acc[2][0] += a.z * b.x; acc[2][1] += a.z * b.y; acc[2][2] += a.z * b.z; acc[2][3] += a.z * b.w;
      acc[3][0] += a.w * b.x; acc[3][1] += a.w * b.y; acc[3][2] += a.w * b.z; acc[3][3] += a.w * b.w;
    }
    __syncthreads();
  }
#pragma unroll
  for (int i = 0; i < 4; ++i) {
    int m = m0 + (ty << 2) + i;
#pragma unroll
    for (int j = 0; j < 4; ++j) {
      int n = n0 + (tx << 2) + j;
      if (n < NG) pre[(size_t)m * NG + n] = acc[i][j] + bih[n] + bhh[n];
    }
  }
}

// ---------------------------------------------------------------- sync init
// hbuf: 2*HSLOT u32 slots, each = (f16_h_bits << 16) | step_tag16.
// All zero => buffer0 tag 0 with h=0.0 is the valid h_0; buffer1 wants odd tags.
__global__ void init_sync(uint* hbuf) {
  int i = threadIdx.x;
  if (i < 2 * HSLOT) hbuf[i] = 0u;
}

// ---------------------------------------------------------------- recurrence
__device__ __forceinline__ float sigm(float x) { return 1.f / (1.f + __expf(-x)); }
__device__ __forceinline__ float fast_tanh(float x) {
  x = fminf(fmaxf(x, -15.f), 15.f);
  float e = __expf(2.f * x);
  return (e - 1.f) / (e + 1.f);
}
__device__ __forceinline__ f16x2 as_f16x2(uint u) {
  union { uint i; f16x2 h; } c; c.i = u; return c.h;
}
__device__ __forceinline__ uint f2h16(float f) {
  union { _Float16 h; unsigned short u; } c; c.h = (_Float16)f; return (uint)c.u;
}
__device__ __forceinline__ uint pack_h2(float a, float b) {
  return f2h16(a) | (f2h16(b) << 16);
}
#if __has_builtin(__builtin_amdgcn_fdot2)
__device__ __forceinline__ float FDOT2(f16x2 a, f16x2 b, float c) {
  return __builtin_amdgcn_fdot2(a, b, c, false);
}
#else
__device__ __forceinline__ float FDOT2(f16x2 a, f16x2 b, float c) {
  return c + (float)a.x * (float)b.x + (float)a.y * (float)b.y;
}
#endif

// Lane map: unit = tid>>5 (0..9), gi = (tid>>3)&3 (gate i/f/g/o), cc = tid&7.
// Lane (unit,gi,cc) covers packed half2-cols {q*32 + cc*4 .. +3} for q=0..7 of
// gate row r = gi*UPW + unit.  W LDS is XOR-swizzled: word p stored at
// p ^ ((r&7)*4) -> the wave's 8 distinct rows (distinct mod 8) land on
// disjoint bank groups => 2 lanes/bank, distinct addr = free.
__global__ __launch_bounds__(TPB) void lstm_seq(const float* __restrict__ pre,
                                                const float* __restrict__ Whh,
                                                const float* __restrict__ fcw,
                                                const float* __restrict__ fcb,
                                                uint* hbuf,
                                                float* __restrict__ out) {
  __shared__ uint Wl[RWS][256];     // f16-pair packed, 250 used + pad
  __shared__ uint h2b[2][256];      // double-buffered h as half2
  const int g = blockIdx.x;
  const int tid = threadIdx.x;
  const int unit = tid >> 5;
  const int gi = (tid >> 3) & 3;
  const int cc = tid & 7;
  const int r = gi * UPW + unit;              // local gate row 0..39
  const int swz = (r & 7) * 4;
  const int owner = ((tid & 31) == 0);
  const int base = tid & 32;                  // in-wave group base (0 or 32)
  const int my_prerow = gi * HID + g * UPW + unit;

  // stage W_hh slice as f16 pairs, swizzled
  for (int i = tid; i < RWS * 256; i += TPB) {
    int rr = i >> 8, cp = i & 255;
    int ggi = rr / UPW, ul = rr % UPW;
    size_t grow = (size_t)(ggi * HID + g * UPW + ul) * HID;
    int c0 = cp * 2, c1 = c0 + 1;
    float v0 = (c0 < HID) ? Whh[grow + c0] : 0.f;
    float v1 = (c1 < HID) ? Whh[grow + c1] : 0.f;
    Wl[rr][cp ^ ((rr & 7) * 4)] = pack_h2(v0, v1);
  }

  const uint* wrow = &Wl[r][0];
  const u64* hb64 = (const u64*)hbuf;         // slot pair tid -> u32 slots 2tid,2tid+1
  float c_reg = 0.f;

  for (int t = 0; t < SEQ; ++t) {
    // pre load issued before the spin so its latency overlaps the handshake
    float pre_v = 0.f;
    if (cc == 0) pre_v = pre[(size_t)t * NG + my_prerow];

    // per-lane spin on tagged slots (no per-iteration barrier)
    const uint want = (uint)t & 0xffffu;
    if (tid < 250) {
      const u64* src = hb64 + (size_t)(t & 1) * 256 + tid;
      u64 u;
      do {
        u = __hip_atomic_load(src, __ATOMIC_RELAXED, __HIP_MEMORY_SCOPE_AGENT);
      } while (((uint)u & 0xffffu) != want || ((uint)(u >> 32) & 0xffffu) != want);
      h2b[t & 1][tid] = (((uint)u >> 16) & 0xffffu) | ((uint)(u >> 48) << 16);
    }
    __syncthreads();  // the ONLY barrier per step (h2b double buffer makes it safe)

    // matvec: 8 chunks x 4 half2 per lane = 64 cols, fp32 accumulate
    const uint* h2 = h2b[t & 1];
    float acc = 0.f;
#pragma unroll
    for (int q = 0; q < 8; ++q) {
      uint4 w = *(const uint4*)&wrow[(q * 32 + cc * 4) ^ swz];
      uint4 hh = *(const uint4*)&h2[q * 32 + cc * 4];
      acc = FDOT2(as_f16x2(w.x), as_f16x2(hh.x), acc);
      acc = FDOT2(as_f16x2(w.y), as_f16x2(hh.y), acc);
      acc = FDOT2(as_f16x2(w.z), as_f16x2(hh.z), acc);
      acc = FDOT2(as_f16x2(w.w), as_f16x2(hh.w), acc);
    }
    acc += __shfl_xor(acc, 1);
    acc += __shfl_xor(acc, 2);
    acc += __shfl_xor(acc, 4);
    if (cc == 0) acc += pre_v;   // cc==0 lane of each gate octet holds row sum + pre

    // gather the 4 gate sums into the unit-owner lane (all in-wave, no LDS)
    float si = __shfl(acc, base + 0);
    float sf = __shfl(acc, base + 8);
    float sg = __shfl(acc, base + 16);
    float so = __shfl(acc, base + 24);
    if (owner) {
      float iv = sigm(si);
      float fv = sigm(sf);
      float gv = fast_tanh(sg);
      float ov = sigm(so);
      c_reg = fv * c_reg + iv * gv;
      float h = ov * fast_tanh(c_reg);
      uint pk = (f2h16(h) << 16) | ((uint)(t + 1) & 0xffffu);
      __hip_atomic_store(&hbuf[((t + 1) & 1) * HSLOT + g * UPW + unit], pk,
                         __ATOMIC_RELAXED, __HIP_MEMORY_SCOPE_AGENT);
    }
  }

  // final FC by WG 0: out = fc_w @ h_SEQ + fc_b   (h_SEQ in buffer SEQ&1 = 0)
  if (g == 0) {
    const uint want = (uint)SEQ & 0xffffu;
    if (tid < 250) {
      const u64* src = hb64 + tid;   // buffer 0
      u64 u;
      do {
        u = __hip_atomic_load(src, __ATOMIC_RELAXED, __HIP_MEMORY_SCOPE_AGENT);
      } while (((uint)u & 0xffffu) != want || ((uint)(u >> 32) & 0xffffu) != want);
      h2b[0][tid] = (((uint)u >> 16) & 0xffffu) | ((uint)(u >> 48) << 16);
    }
    __syncthreads();
    int row = tid >> 4, ln = tid & 15;   // 20 rows x 16 lanes = 320
    float s = 0.f;
    for (int j = ln; j < HID; j += 16) {
      f16x2 p = as_f16x2(h2b[0][j >> 1]);
      float hv = (j & 1) ? (float)p.y : (float)p.x;
      s += fcw[row * HID + j] * hv;
    }
    s += __shfl_xor(s, 1); s += __shfl_xor(s, 2);
    s += __shfl_xor(s, 4); s += __shfl_xor(s, 8);
    if (ln == 0) out[row] = s + fcb[row];
  }
}

// ---------------------------------------------------------------- launch
extern "C" void kernel_launch(void* const* d_in, const int* in_sizes, int n_in,
                              void* d_out, int out_size, void* d_ws, size_t ws_size,
                              hipStream_t stream) {
  const int* words = (const int*)d_in[0];
  const int* labels = (const int*)d_in[1];
  const float* embw = (const float*)d_in[2];
  const float* embe = (const float*)d_in[3];
  const float* Wih = (const float*)d_in[4];
  const float* Whh = (const float*)d_in[5];
  const float* bih = (const float*)d_in[6];
  const float* bhh = (const float*)d_in[7];
  const float* fcw = (const float*)d_in[8];
  const float* fcb = (const float*)d_in[9];
  float* out = (float*)d_out;

  char* ws = (char*)d_ws;
  float* x = (float*)ws;                                             // 4096*608*4  = 9.96 MB
  float* pre = (float*)(ws + (size_t)SEQ * KXP * 4);                 // 4096*2000*4 = 32.77 MB
  uint* hbuf = (uint*)(ws + (size_t)SEQ * KXP * 4 + (size_t)SEQ * NG * 4);  // 2*512*4 = 4 KB

  gather_x<<<SEQ, 256, 0, stream>>>(words, labels, embw, embe, x);
  dim3 ggrid(SEQ / BM, (NG + BN - 1) / BN);
  gemm_pre<<<ggrid, 256, 0, stream>>>(x, Wih, bih, bhh, pre);
  init_sync<<<1, 1024, 0, stream>>>(hbuf);
  lstm_seq<<<NWG, TPB, 0, stream>>>(pre, Whh, fcw, fcb, hbuf, out);
}

// Round 5
// 10611.995 us; speedup vs baseline: 1.1924x; 1.1924x over previous
//
#include <hip/hip_runtime.h>

typedef unsigned int uint;
typedef unsigned long long u64;
typedef _Float16 f16x2 __attribute__((ext_vector_type(2)));

#define SEQ 4096
#define EMB 300
#define HID 500
#define NG 2000      // 4*HID
#define KX 600       // 2*EMB
#define KXP 608      // padded K for aligned float4 loads

#define BM 64
#define BN 64
#define BK 16

#define NWG 25       // workgroups in recurrence
#define UPW 20       // hidden units per workgroup
#define TPB 640      // 20 units * 32 lanes (4 gates x 8 col-chunk lanes)
#define HSLOT 512    // padded u32 h slots per double-buffer half

// ---------------------------------------------------------------- gather x
__global__ __launch_bounds__(256) void gather_x(const int* __restrict__ words,
                                                const int* __restrict__ labels,
                                                const float* __restrict__ embw,
                                                const float* __restrict__ embe,
                                                float* __restrict__ x) {
  int t = blockIdx.x;
  int w = words[t], l = labels[t];
  const float* rw = embw + (size_t)w * EMB;
  const float* re = embe + (size_t)l * EMB;
  float* xr = x + (size_t)t * KXP;
  for (int k = threadIdx.x; k < KXP; k += 256) {
    float v = 0.f;
    if (k < EMB) v = rw[k];
    else if (k < KX) v = re[k - EMB];
    xr[k] = v;  // pads [600,608) zeroed
  }
}

// ---------------------------------------------------------------- pre GEMM
// pre[t][n] = sum_k x[t][k] * Wih[n][k] + bih[n] + bhh[n]
__global__ __launch_bounds__(256) void gemm_pre(const float* __restrict__ x,
                                                const float* __restrict__ Wih,
                                                const float* __restrict__ bih,
                                                const float* __restrict__ bhh,
                                                float* __restrict__ pre) {
  __shared__ float As[BK][BM + 4];
  __shared__ float Bs[BK][BN + 4];
  const int m0 = blockIdx.x * BM;
  const int n0 = blockIdx.y * BN;
  const int tid = threadIdx.x;
  const int tx = tid & 15, ty = tid >> 4;
  const int lrow = tid >> 2;          // 0..63
  const int lc4 = (tid & 3) << 2;     // 0,4,8,12
  float acc[4][4] = {};

  for (int kk = 0; kk < KX; kk += BK) {
    float4 av = *(const float4*)(x + (size_t)(m0 + lrow) * KXP + kk + lc4);
    int brow = n0 + lrow; if (brow >= NG) brow = 0;
    float4 bv;
    if (kk + lc4 + 3 < KX) {
      bv = *(const float4*)(Wih + (size_t)brow * KX + kk + lc4);
    } else {
      float tmp[4];
#pragma unroll
      for (int j = 0; j < 4; ++j) {
        int k = kk + lc4 + j;
        tmp[j] = (k < KX) ? Wih[(size_t)brow * KX + k] : 0.f;
      }
      bv = make_float4(tmp[0], tmp[1], tmp[2], tmp[3]);
    }
    As[lc4 + 0][lrow] = av.x; As[lc4 + 1][lrow] = av.y;
    As[lc4 + 2][lrow] = av.z; As[lc4 + 3][lrow] = av.w;
    Bs[lc4 + 0][lrow] = bv.x; Bs[lc4 + 1][lrow] = bv.y;
    Bs[lc4 + 2][lrow] = bv.z; Bs[lc4 + 3][lrow] = bv.w;
    __syncthreads();
#pragma unroll
    for (int k = 0; k < BK; ++k) {
      float4 a = *(const float4*)&As[k][ty << 2];
      float4 b = *(const float4*)&Bs[k][tx << 2];
      acc[0][0] += a.x * b.x; acc[0][1] += a.x * b.y; acc[0][2] += a.x * b.z; acc[0][3] += a.x * b.w;
      acc[1][0] += a.y * b.x; acc[1][1] += a.y * b.y; acc[1][2] += a.y * b.z; acc[1][3] += a.y * b.w;
      acc[2][0] += a.z * b.x; acc[2][1] += a.z * b.y; acc[2][2] += a.z * b.z; acc[2][3] += a.z * b.w;
      acc[3][0] += a.w * b.x; acc[3][1] += a.w * b.y; acc[3][2] += a.w * b.z; acc[3][3] += a.w * b.w;
    }
    __syncthreads();
  }
#pragma unroll
  for (int i = 0; i < 4; ++i) {
    int m = m0 + (ty << 2) + i;
#pragma unroll
    for (int j = 0; j < 4; ++j) {
      int n = n0 + (tx << 2) + j;
      if (n < NG) pre[(size_t)m * NG + n] = acc[i][j] + bih[n] + bhh[n];
    }
  }
}

// ---------------------------------------------------------------- sync init
// hbuf: 2*HSLOT u32 slots, each = (f16_h_bits << 16) | step_tag16.
// All zero => buffer0 tag 0 with h=0.0 is the valid h_0; buffer1 wants odd tags.
__global__ void init_sync(uint* hbuf) {
  int i = threadIdx.x;
  if (i < 2 * HSLOT) hbuf[i] = 0u;
}

// ---------------------------------------------------------------- recurrence
__device__ __forceinline__ float sigm(float x) { return 1.f / (1.f + __expf(-x)); }
__device__ __forceinline__ float fast_tanh(float x) {
  x = fminf(fmaxf(x, -15.f), 15.f);
  float e = __expf(2.f * x);
  return (e - 1.f) / (e + 1.f);
}
__device__ __forceinline__ f16x2 as_f16x2(uint u) {
  union { uint i; f16x2 h; } c; c.i = u; return c.h;
}
__device__ __forceinline__ uint f2h16(float f) {
  union { _Float16 h; unsigned short u; } c; c.h = (_Float16)f; return (uint)c.u;
}
#if __has_builtin(__builtin_amdgcn_fdot2)
__device__ __forceinline__ float FDOT2(f16x2 a, f16x2 b, float c) {
  return __builtin_amdgcn_fdot2(a, b, c, false);
}
#else
__device__ __forceinline__ float FDOT2(f16x2 a, f16x2 b, float c) {
  return c + (float)a.x * (float)b.x + (float)a.y * (float)b.y;
}
#endif

#define TAGMASK 0x0000FFFF0000FFFFull

// Lane map: unit = tid>>5 (0..19), gi = (tid>>3)&3 (gate i/f/g/o), cc = tid&7.
// Lane (unit,gi,cc) owns gate row r = gi*UPW + unit and its 64 cols
// {64q + 8cc .. +7 | q=0..7}, held in 32 VGPRs as f16 pairs (no W LDS at all).
__global__ __launch_bounds__(TPB) void lstm_seq(const float* __restrict__ pre,
                                                const float* __restrict__ Whh,
                                                const float* __restrict__ fcw,
                                                const float* __restrict__ fcb,
                                                uint* hbuf,
                                                float* __restrict__ out) {
  __shared__ uint h2b[2][256];      // double-buffered h as half2 pairs
  const int g = blockIdx.x;
  const int tid = threadIdx.x;
  const int unit = tid >> 5;
  const int gi = (tid >> 3) & 3;
  const int cc = tid & 7;
  const int owner = ((tid & 31) == 0);
  const int base = tid & 32;                  // in-wave 32-group base (0 or 32)
  const int my_prerow = gi * HID + g * UPW + unit;

  // zero ALL of h2b (slots [250,256) of each half are READ by the matvec as
  // padding but never written by pollers — leaving them uninitialized was the
  // R4 NaN: 0-weight * NaN-pattern LDS residue = NaN).  Data slots are
  // rewritten by the same/ordered threads after the step-0/1 barriers.
  for (int i = tid; i < 512; i += TPB) ((uint*)h2b)[i] = 0u;

  // stage this lane's W_hh row-slice into registers (f16 pairs)
  uint wreg[32];
  {
    size_t grow = (size_t)(gi * HID + g * UPW + unit) * HID;
#pragma unroll
    for (int q = 0; q < 8; ++q) {
#pragma unroll
      for (int j = 0; j < 4; ++j) {
        int word = q * 32 + cc * 4 + j;       // packed half2 index 0..255
        int c2 = word * 2;
        float v0 = (c2 < HID) ? Whh[grow + c2] : 0.f;
        float v1 = (c2 + 1 < HID) ? Whh[grow + c2 + 1] : 0.f;
        wreg[q * 4 + j] = f2h16(v0) | (f2h16(v1) << 16);
      }
    }
  }

  const u64* hb64 = (const u64*)hbuf;         // pair i covers u32 slots 2i,2i+1
  float c_reg = 0.f;

  for (int t = 0; t < SEQ; ++t) {
    // pre load issued before the spin so its latency overlaps the handshake
    float pre_v = 0.f;
    if (cc == 0) pre_v = pre[(size_t)t * NG + my_prerow];

    // per-lane spin on tagged pairs, two samples in flight
    const u64 want2 = (u64)((uint)t & 0xffffu) * 0x0000000100000001ull;
    if (tid < 250) {
      const u64* src = hb64 + (size_t)(t & 1) * 256 + tid;
      u64 a = __hip_atomic_load(src, __ATOMIC_RELAXED, __HIP_MEMORY_SCOPE_AGENT);
      u64 b = __hip_atomic_load(src, __ATOMIC_RELAXED, __HIP_MEMORY_SCOPE_AGENT);
      for (;;) {
        if ((a & TAGMASK) == want2) break;
        if ((b & TAGMASK) == want2) { a = b; break; }
        a = __hip_atomic_load(src, __ATOMIC_RELAXED, __HIP_MEMORY_SCOPE_AGENT);
        b = __hip_atomic_load(src, __ATOMIC_RELAXED, __HIP_MEMORY_SCOPE_AGENT);
      }
      h2b[t & 1][tid] = (((uint)(a >> 16)) & 0xffffu) | (((uint)(a >> 48)) << 16);
    }
    __syncthreads();  // the ONLY barrier per step (double buffer makes it safe)

    // matvec: 8 chunks x 4 half2 from registers vs LDS h (broadcast reads)
    const uint* h2 = h2b[t & 1];
    float acc = 0.f;
#pragma unroll
    for (int q = 0; q < 8; ++q) {
      uint4 hh = *(const uint4*)&h2[q * 32 + cc * 4];
      acc = FDOT2(as_f16x2(wreg[q * 4 + 0]), as_f16x2(hh.x), acc);
      acc = FDOT2(as_f16x2(wreg[q * 4 + 1]), as_f16x2(hh.y), acc);
      acc = FDOT2(as_f16x2(wreg[q * 4 + 2]), as_f16x2(hh.z), acc);
      acc = FDOT2(as_f16x2(wreg[q * 4 + 3]), as_f16x2(hh.w), acc);
    }
    acc += __shfl_xor(acc, 1);
    acc += __shfl_xor(acc, 2);
    acc += __shfl_xor(acc, 4);
    if (cc == 0) acc += pre_v;   // cc==0 lane of each gate octet holds row sum

    // gather the 4 gate sums into the unit-owner lane (in-wave)
    float si = __shfl(acc, base + 0);
    float sf = __shfl(acc, base + 8);
    float sg = __shfl(acc, base + 16);
    float so = __shfl(acc, base + 24);
    if (owner) {
      float iv = sigm(si);
      float fv = sigm(sf);
      float gv = fast_tanh(sg);
      float ov = sigm(so);
      c_reg = fv * c_reg + iv * gv;
      float h = ov * fast_tanh(c_reg);
      uint pk = (f2h16(h) << 16) | ((uint)(t + 1) & 0xffffu);
      __hip_atomic_store(&hbuf[((t + 1) & 1) * HSLOT + g * UPW + unit], pk,
                         __ATOMIC_RELAXED, __HIP_MEMORY_SCOPE_AGENT);
    }
  }

  // final FC by WG 0: out = fc_w @ h_SEQ + fc_b   (h_SEQ in buffer SEQ&1 = 0)
  if (g == 0) {
    const u64 want2 = (u64)((uint)SEQ & 0xffffu) * 0x0000000100000001ull;
    if (tid < 250) {
      const u64* src = hb64 + tid;   // buffer 0
      u64 a;
      do {
        a = __hip_atomic_load(src, __ATOMIC_RELAXED, __HIP_MEMORY_SCOPE_AGENT);
      } while ((a & TAGMASK) != want2);
      h2b[0][tid] = (((uint)(a >> 16)) & 0xffffu) | (((uint)(a >> 48)) << 16);
    }
    __syncthreads();
    int row = tid >> 5, ln = tid & 31;   // 20 rows x 32 lanes = 640
    float s = 0.f;
    for (int j = ln; j < HID; j += 32) {
      f16x2 p = as_f16x2(h2b[0][j >> 1]);
      float hv = (j & 1) ? (float)p.y : (float)p.x;
      s += fcw[row * HID + j] * hv;
    }
    s += __shfl_xor(s, 1); s += __shfl_xor(s, 2);
    s += __shfl_xor(s, 4); s += __shfl_xor(s, 8);
    s += __shfl_xor(s, 16);
    if (ln == 0) out[row] = s + fcb[row];
  }
}

// ---------------------------------------------------------------- launch
extern "C" void kernel_launch(void* const* d_in, const int* in_sizes, int n_in,
                              void* d_out, int out_size, void* d_ws, size_t ws_size,
                              hipStream_t stream) {
  const int* words = (const int*)d_in[0];
  const int* labels = (const int*)d_in[1];
  const float* embw = (const float*)d_in[2];
  const float* embe = (const float*)d_in[3];
  const float* Wih = (const float*)d_in[4];
  const float* Whh = (const float*)d_in[5];
  const float* bih = (const float*)d_in[6];
  const float* bhh = (const float*)d_in[7];
  const float* fcw = (const float*)d_in[8];
  const float* fcb = (const float*)d_in[9];
  float* out = (float*)d_out;

  char* ws = (char*)d_ws;
  float* x = (float*)ws;                                             // 4096*608*4  = 9.96 MB
  float* pre = (float*)(ws + (size_t)SEQ * KXP * 4);                 // 4096*2000*4 = 32.77 MB
  uint* hbuf = (uint*)(ws + (size_t)SEQ * KXP * 4 + (size_t)SEQ * NG * 4);  // 2*512*4 = 4 KB

  gather_x<<<SEQ, 256, 0, stream>>>(words, labels, embw, embe, x);
  dim3 ggrid(SEQ / BM, (NG + BN - 1) / BN);
  gemm_pre<<<ggrid, 256, 0, stream>>>(x, Wih, bih, bhh, pre);
  init_sync<<<1, 1024, 0, stream>>>(hbuf);
  lstm_seq<<<NWG, TPB, 0, stream>>>(pre, Whh, fcw, fcb, hbuf, out);
}

// Round 6
// 9292.607 us; speedup vs baseline: 1.3617x; 1.1420x over previous
//
#include <hip/hip_runtime.h>

typedef unsigned int uint;
typedef unsigned long long u64;
typedef _Float16 f16x2 __attribute__((ext_vector_type(2)));

#define SEQ 4096
#define EMB 300
#define HID 500
#define NG 2000      // 4*HID
#define KX 600       // 2*EMB
#define KXP 608      // padded K for aligned float4 loads

#define BM 64
#define BN 64
#define BK 16

#define NWG 25       // workgroups in recurrence
#define UPW 20       // hidden units per workgroup
#define TPB 640      // 20 units * 32 lanes (4 gates x 8 col-chunk lanes)

// Exchange layout: 250 u64 "pairs" (units 2p,2p+1 as tagged u32 each),
// each pair padded to its own 64B cache line -> per-line sharing = 25 pollers
// instead of ~200.  Double buffered: half b at u64 offset b*HHALF.
#define HPAIR 8                    // u64 stride per pair = 64 B
#define HHALF (250 * HPAIR)        // u64s per buffer half
#define HTOT  (2 * HHALF)          // 4000 u64 = 32 KB

// ---------------------------------------------------------------- gather x
__global__ __launch_bounds__(256) void gather_x(const int* __restrict__ words,
                                                const int* __restrict__ labels,
                                                const float* __restrict__ embw,
                                                const float* __restrict__ embe,
                                                float* __restrict__ x) {
  int t = blockIdx.x;
  int w = words[t], l = labels[t];
  const float* rw = embw + (size_t)w * EMB;
  const float* re = embe + (size_t)l * EMB;
  float* xr = x + (size_t)t * KXP;
  for (int k = threadIdx.x; k < KXP; k += 256) {
    float v = 0.f;
    if (k < EMB) v = rw[k];
    else if (k < KX) v = re[k - EMB];
    xr[k] = v;  // pads [600,608) zeroed
  }
}

// ---------------------------------------------------------------- pre GEMM
// pre[t][n] = sum_k x[t][k] * Wih[n][k] + bih[n] + bhh[n]
__global__ __launch_bounds__(256) void gemm_pre(const float* __restrict__ x,
                                                const float* __restrict__ Wih,
                                                const float* __restrict__ bih,
                                                const float* __restrict__ bhh,
                                                float* __restrict__ pre) {
  __shared__ float As[BK][BM + 4];
  __shared__ float Bs[BK][BN + 4];
  const int m0 = blockIdx.x * BM;
  const int n0 = blockIdx.y * BN;
  const int tid = threadIdx.x;
  const int tx = tid & 15, ty = tid >> 4;
  const int lrow = tid >> 2;          // 0..63
  const int lc4 = (tid & 3) << 2;     // 0,4,8,12
  float acc[4][4] = {};

  for (int kk = 0; kk < KX; kk += BK) {
    float4 av = *(const float4*)(x + (size_t)(m0 + lrow) * KXP + kk + lc4);
    int brow = n0 + lrow; if (brow >= NG) brow = 0;
    float4 bv;
    if (kk + lc4 + 3 < KX) {
      bv = *(const float4*)(Wih + (size_t)brow * KX + kk + lc4);
    } else {
      float tmp[4];
#pragma unroll
      for (int j = 0; j < 4; ++j) {
        int k = kk + lc4 + j;
        tmp[j] = (k < KX) ? Wih[(size_t)brow * KX + k] : 0.f;
      }
      bv = make_float4(tmp[0], tmp[1], tmp[2], tmp[3]);
    }
    As[lc4 + 0][lrow] = av.x; As[lc4 + 1][lrow] = av.y;
    As[lc4 + 2][lrow] = av.z; As[lc4 + 3][lrow] = av.w;
    Bs[lc4 + 0][lrow] = bv.x; Bs[lc4 + 1][lrow] = bv.y;
    Bs[lc4 + 2][lrow] = bv.z; Bs[lc4 + 3][lrow] = bv.w;
    __syncthreads();
#pragma unroll
    for (int k = 0; k < BK; ++k) {
      float4 a = *(const float4*)&As[k][ty << 2];
      float4 b = *(const float4*)&Bs[k][tx << 2];
      acc[0][0] += a.x * b.x; acc[0][1] += a.x * b.y; acc[0][2] += a.x * b.z; acc[0][3] += a.x * b.w;
      acc[1][0] += a.y * b.x; acc[1][1] += a.y * b.y; acc[1][2] += a.y * b.z; acc[1][3] += a.y * b.w;
      acc[2][0] += a.z * b.x; acc[2][1] += a.z * b.y; acc[2][2] += a.z * b.z; acc[2][3] += a.z * b.w;
      acc[3][0] += a.w * b.x; acc[3][1] += a.w * b.y; acc[3][2] += a.w * b.z; acc[3][3] += a.w * b.w;
    }
    __syncthreads();
  }
#pragma unroll
  for (int i = 0; i < 4; ++i) {
    int m = m0 + (ty << 2) + i;
#pragma unroll
    for (int j = 0; j < 4; ++j) {
      int n = n0 + (tx << 2) + j;
      if (n < NG) pre[(size_t)m * NG + n] = acc[i][j] + bih[n] + bhh[n];
    }
  }
}

// ---------------------------------------------------------------- sync init
// Slot u32 = (f16_h_bits << 16) | step_tag16.  All-zero => buffer0 tag 0 with
// h=0.0 is the valid h_0; buffer1 wants odd tags so 0 never matches.
__global__ void init_sync(u64* hbuf) {
  for (int i = threadIdx.x; i < HTOT; i += 1024) hbuf[i] = 0ull;
}

// ---------------------------------------------------------------- recurrence
__device__ __forceinline__ float sigm(float x) { return 1.f / (1.f + __expf(-x)); }
__device__ __forceinline__ float fast_tanh(float x) {
  x = fminf(fmaxf(x, -15.f), 15.f);
  float e = __expf(2.f * x);
  return (e - 1.f) / (e + 1.f);
}
__device__ __forceinline__ f16x2 as_f16x2(uint u) {
  union { uint i; f16x2 h; } c; c.i = u; return c.h;
}
__device__ __forceinline__ uint f2h16(float f) {
  union { _Float16 h; unsigned short u; } c; c.h = (_Float16)f; return (uint)c.u;
}
#if __has_builtin(__builtin_amdgcn_fdot2)
__device__ __forceinline__ float FDOT2(f16x2 a, f16x2 b, float c) {
  return __builtin_amdgcn_fdot2(a, b, c, false);
}
#else
__device__ __forceinline__ float FDOT2(f16x2 a, f16x2 b, float c) {
  return c + (float)a.x * (float)b.x + (float)a.y * (float)b.y;
}
#endif

#define TAGMASK 0x0000FFFF0000FFFFull

// Lane map: unit = tid>>5 (0..19), gi = (tid>>3)&3 (gate i/f/g/o), cc = tid&7.
// Lane (unit,gi,cc) owns gate row r = gi*UPW + unit and its 64 cols
// {64q + 8cc .. +7 | q=0..7}, held in 32 VGPRs as f16 pairs (no W LDS at all).
__global__ __launch_bounds__(TPB) void lstm_seq(const float* __restrict__ pre,
                                                const float* __restrict__ Whh,
                                                const float* __restrict__ fcw,
                                                const float* __restrict__ fcb,
                                                uint* hbuf,
                                                float* __restrict__ out) {
  __shared__ uint h2b[2][256];      // double-buffered h as half2 pairs
  const int g = blockIdx.x;
  const int tid = threadIdx.x;
  const int unit = tid >> 5;
  const int gi = (tid >> 3) & 3;
  const int cc = tid & 7;
  const int owner = ((tid & 31) == 0);
  const int base = tid & 32;                  // in-wave 32-group base (0 or 32)
  const int my_prerow = gi * HID + g * UPW + unit;
  const int my_unit = g * UPW + unit;         // global unit id this lane-group owns
  // padded u32 slot index for unit u, buffer b: b*2*HHALF + (u>>1)*2*HPAIR + (u&1)
  const int my_slot = (my_unit >> 1) * (2 * HPAIR) + (my_unit & 1);

  // zero ALL of h2b (slots [250,256) of each half are READ by the matvec as
  // padding but never written by pollers — uninitialized LDS residue there was
  // the R4 NaN).  Data slots are rewritten after the step-0/1 barriers.
  for (int i = tid; i < 512; i += TPB) ((uint*)h2b)[i] = 0u;

  // stage this lane's W_hh row-slice into registers (f16 pairs)
  uint wreg[32];
  {
    size_t grow = (size_t)(gi * HID + g * UPW + unit) * HID;
#pragma unroll
    for (int q = 0; q < 8; ++q) {
#pragma unroll
      for (int j = 0; j < 4; ++j) {
        int word = q * 32 + cc * 4 + j;       // packed half2 index 0..255
        int c2 = word * 2;
        float v0 = (c2 < HID) ? Whh[grow + c2] : 0.f;
        float v1 = (c2 + 1 < HID) ? Whh[grow + c2 + 1] : 0.f;
        wreg[q * 4 + j] = f2h16(v0) | (f2h16(v1) << 16);
      }
    }
  }

  const u64* hb64 = (const u64*)hbuf;   // pair p lives at u64 index p*HPAIR
  float c_reg = 0.f;

  for (int t = 0; t < SEQ; ++t) {
    // pre load issued before the spin so its latency overlaps the handshake
    float pre_v = 0.f;
    if (cc == 0) pre_v = pre[(size_t)t * NG + my_prerow];

    // per-lane spin on this lane's padded tagged pair, two samples in flight
    const u64 want2 = (u64)((uint)t & 0xffffu) * 0x0000000100000001ull;
    if (tid < 250) {
      const u64* src = hb64 + (size_t)(t & 1) * HHALF + (size_t)tid * HPAIR;
      u64 a = __hip_atomic_load(src, __ATOMIC_RELAXED, __HIP_MEMORY_SCOPE_AGENT);
      u64 b = __hip_atomic_load(src, __ATOMIC_RELAXED, __HIP_MEMORY_SCOPE_AGENT);
      for (;;) {
        if ((a & TAGMASK) == want2) break;
        if ((b & TAGMASK) == want2) { a = b; break; }
        a = __hip_atomic_load(src, __ATOMIC_RELAXED, __HIP_MEMORY_SCOPE_AGENT);
        b = __hip_atomic_load(src, __ATOMIC_RELAXED, __HIP_MEMORY_SCOPE_AGENT);
      }
      h2b[t & 1][tid] = (((uint)(a >> 16)) & 0xffffu) | (((uint)(a >> 48)) << 16);
    }
    __syncthreads();  // the ONLY barrier per step (double buffer makes it safe)

    // matvec: 8 chunks x 4 half2 from registers vs LDS h (broadcast reads)
    const uint* h2 = h2b[t & 1];
    float acc = 0.f;
#pragma unroll
    for (int q = 0; q < 8; ++q) {
      uint4 hh = *(const uint4*)&h2[q * 32 + cc * 4];
      acc = FDOT2(as_f16x2(wreg[q * 4 + 0]), as_f16x2(hh.x), acc);
      acc = FDOT2(as_f16x2(wreg[q * 4 + 1]), as_f16x2(hh.y), acc);
      acc = FDOT2(as_f16x2(wreg[q * 4 + 2]), as_f16x2(hh.z), acc);
      acc = FDOT2(as_f16x2(wreg[q * 4 + 3]), as_f16x2(hh.w), acc);
    }
    acc += __shfl_xor(acc, 1);
    acc += __shfl_xor(acc, 2);
    acc += __shfl_xor(acc, 4);
    if (cc == 0) acc += pre_v;   // cc==0 lane of each gate octet holds row sum

    // gather the 4 gate sums into the unit-owner lane (in-wave)
    float si = __shfl(acc, base + 0);
    float sf = __shfl(acc, base + 8);
    float sg = __shfl(acc, base + 16);
    float so = __shfl(acc, base + 24);
    if (owner) {
      float iv = sigm(si);
      float fv = sigm(sf);
      float gv = fast_tanh(sg);
      float ov = sigm(so);
      c_reg = fv * c_reg + iv * gv;
      float h = ov * fast_tanh(c_reg);
      uint pk = (f2h16(h) << 16) | ((uint)(t + 1) & 0xffffu);
      __hip_atomic_store(&hbuf[((t + 1) & 1) * (2 * HHALF) + my_slot], pk,
                         __ATOMIC_RELAXED, __HIP_MEMORY_SCOPE_AGENT);
    }
  }

  // final FC by WG 0: out = fc_w @ h_SEQ + fc_b   (h_SEQ in buffer SEQ&1 = 0)
  if (g == 0) {
    const u64 want2 = (u64)((uint)SEQ & 0xffffu) * 0x0000000100000001ull;
    if (tid < 250) {
      const u64* src = hb64 + (size_t)tid * HPAIR;   // buffer 0
      u64 a;
      do {
        a = __hip_atomic_load(src, __ATOMIC_RELAXED, __HIP_MEMORY_SCOPE_AGENT);
      } while ((a & TAGMASK) != want2);
      h2b[0][tid] = (((uint)(a >> 16)) & 0xffffu) | (((uint)(a >> 48)) << 16);
    }
    __syncthreads();
    int row = tid >> 5, ln = tid & 31;   // 20 rows x 32 lanes = 640
    float s = 0.f;
    for (int j = ln; j < HID; j += 32) {
      f16x2 p = as_f16x2(h2b[0][j >> 1]);
      float hv = (j & 1) ? (float)p.y : (float)p.x;
      s += fcw[row * HID + j] * hv;
    }
    s += __shfl_xor(s, 1); s += __shfl_xor(s, 2);
    s += __shfl_xor(s, 4); s += __shfl_xor(s, 8);
    s += __shfl_xor(s, 16);
    if (ln == 0) out[row] = s + fcb[row];
  }
}

// ---------------------------------------------------------------- launch
extern "C" void kernel_launch(void* const* d_in, const int* in_sizes, int n_in,
                              void* d_out, int out_size, void* d_ws, size_t ws_size,
                              hipStream_t stream) {
  const int* words = (const int*)d_in[0];
  const int* labels = (const int*)d_in[1];
  const float* embw = (const float*)d_in[2];
  const float* embe = (const float*)d_in[3];
  const float* Wih = (const float*)d_in[4];
  const float* Whh = (const float*)d_in[5];
  const float* bih = (const float*)d_in[6];
  const float* bhh = (const float*)d_in[7];
  const float* fcw = (const float*)d_in[8];
  const float* fcb = (const float*)d_in[9];
  float* out = (float*)d_out;

  char* ws = (char*)d_ws;
  float* x = (float*)ws;                                             // 4096*608*4  = 9.96 MB
  float* pre = (float*)(ws + (size_t)SEQ * KXP * 4);                 // 4096*2000*4 = 32.77 MB
  uint* hbuf = (uint*)(ws + (size_t)SEQ * KXP * 4 + (size_t)SEQ * NG * 4);  // 32 KB padded exchange

  gather_x<<<SEQ, 256, 0, stream>>>(words, labels, embw, embe, x);
  dim3 ggrid(SEQ / BM, (NG + BN - 1) / BN);
  gemm_pre<<<ggrid, 256, 0, stream>>>(x, Wih, bih, bhh, pre);
  init_sync<<<1, 1024, 0, stream>>>((u64*)hbuf);
  lstm_seq<<<NWG, TPB, 0, stream>>>(pre, Whh, fcw, fcb, hbuf, out);
}